// Round 1
// baseline (246.358 us; speedup 1.0000x reference)
//
#include <hip/hip_runtime.h>
#include <hip/hip_bf16.h>

#define T_TOKENS 16384
#define HIDDEN   2048
#define NEXP     64
#define TOPK     8
#define TOPKG    4
#define RSCALE   2.5f
#define TB       16            // tokens per block
#define CH       128           // hidden chunk (floats)
#define NCH      (HIDDEN / CH) // 16
#define WPAD     132           // padded W row in LDS (floats, keeps 16B align)
#define NBLK     (T_TOKENS / TB) // 1024

// ---------------------------------------------------------------------------
// Kernel 1: fused router GEMM + sigmoid + group top-4 + top-8 + renorm.
// block = 256 threads (4 waves); wave w handles tokens base+4w..base+4w+3;
// lane index == expert index.
// ---------------------------------------------------------------------------
__global__ __launch_bounds__(256)
void router_kernel(const float* __restrict__ tokens,
                   const float* __restrict__ W,
                   float* __restrict__ out,
                   float* __restrict__ wsP,   // per-block (or atomic) prob sums [.. ][64]
                   float* __restrict__ wsC,   // per-block (or atomic) counts    [..][64]
                   int atomicMode)
{
    __shared__ float tokLds[TB * CH];        // 8 KB
    __shared__ float wLds[NEXP * WPAD];      // 33 KB
    __shared__ float redP[4][64];            // 1 KB
    __shared__ float redC[4][64];            // 1 KB

    const int tid  = threadIdx.x;
    const int wv   = tid >> 6;
    const int lane = tid & 63;
    const int base = blockIdx.x * TB;

    float acc[4] = {0.f, 0.f, 0.f, 0.f};

    const float4* tok4 = (const float4*)tokens;
    const float4* w4   = (const float4*)W;

    for (int c = 0; c < NCH; ++c) {
        // stage 16 x 128 token chunk: 512 float4 over 256 threads
        #pragma unroll
        for (int it = 0; it < 2; ++it) {
            int idx = it * 256 + tid;            // 0..511
            int t   = idx >> 5;
            int h4  = idx & 31;
            ((float4*)tokLds)[t * 32 + h4] =
                tok4[(size_t)(base + t) * (HIDDEN / 4) + c * 32 + h4];
        }
        // stage 64 x 128 W chunk (padded rows): 2048 float4 over 256 threads
        #pragma unroll
        for (int it = 0; it < 8; ++it) {
            int idx = it * 256 + tid;            // 0..2047
            int e   = idx >> 5;
            int h4  = idx & 31;
            *(float4*)&wLds[e * WPAD + h4 * 4] =
                w4[(size_t)e * (HIDDEN / 4) + c * 32 + h4];
        }
        __syncthreads();

        #pragma unroll 8
        for (int h4 = 0; h4 < 32; ++h4) {
            float4 wvv = *(const float4*)&wLds[lane * WPAD + h4 * 4];
            #pragma unroll
            for (int t = 0; t < 4; ++t) {
                float4 tv = *(const float4*)&tokLds[(wv * 4 + t) * CH + h4 * 4];
                acc[t] = fmaf(wvv.x, tv.x, acc[t]);
                acc[t] = fmaf(wvv.y, tv.y, acc[t]);
                acc[t] = fmaf(wvv.z, tv.z, acc[t]);
                acc[t] = fmaf(wvv.w, tv.w, acc[t]);
            }
        }
        __syncthreads();
    }

    // ---- epilogue: per-wave, 4 tokens, scores live one-per-lane ----
    float psum = 0.f;   // sum over my tokens of normed score for expert=lane
    float cnt  = 0.f;   // assignment count for expert=lane

    #pragma unroll
    for (int t = 0; t < 4; ++t) {
        const int token = base + wv * 4 + t;
        float s = 1.f / (1.f + expf(-acc[t]));   // sigmoid score, lane=expert

        // group max over 8 consecutive lanes
        float gm = s;
        gm = fmaxf(gm, __shfl_xor(gm, 1));
        gm = fmaxf(gm, __shfl_xor(gm, 2));
        gm = fmaxf(gm, __shfl_xor(gm, 4));

        // rank my group among the 8 group maxima (jax tie-break: lower index)
        const int myg = lane >> 3;
        int rank = 0;
        #pragma unroll
        for (int g = 0; g < 8; ++g) {
            float gs = __shfl(gm, g * 8);
            rank += (gs > gm) || (gs == gm && g < myg);
        }
        float routed = (rank < TOPKG) ? s : 0.f;

        // full-row score sum (for aux normalization)
        float ssum = s;
        #pragma unroll
        for (int off = 1; off < 64; off <<= 1) ssum += __shfl_xor(ssum, off);
        psum += s / fmaxf(ssum, 1e-9f);

        // sequential top-8 wave argmax (value desc, lower index on ties)
        float v = routed;
        int   idx = lane;
        float denom = 0.f;
        float myv = 0.f;
        int   myi = 0;
        #pragma unroll
        for (int k = 0; k < TOPK; ++k) {
            float bv = v;
            int   bi = idx;
            #pragma unroll
            for (int off = 1; off < 64; off <<= 1) {
                float ov = __shfl_xor(bv, off);
                int   oi = __shfl_xor(bi, off);
                if (ov > bv || (ov == bv && oi < bi)) { bv = ov; bi = oi; }
            }
            denom += bv;
            if (lane == k) { myv = bv; myi = bi; }
            if (lane == bi) { v = -1.f; cnt += 1.f; }
        }
        float wscale = RSCALE / fmaxf(denom, 1e-9f);
        if (lane < TOPK) {
            out[(size_t)token * TOPK + lane] = (float)myi;
            out[(size_t)T_TOKENS * TOPK + (size_t)token * TOPK + lane] = myv * wscale;
        }
    }

    // ---- block-level reduction of aux stats ----
    redP[wv][lane] = psum;
    redC[wv][lane] = cnt;
    __syncthreads();
    if (tid < 64) {
        float p = redP[0][tid] + redP[1][tid] + redP[2][tid] + redP[3][tid];
        float c = redC[0][tid] + redC[1][tid] + redC[2][tid] + redC[3][tid];
        if (atomicMode) {
            atomicAdd(&wsP[tid], p);
            atomicAdd(&wsC[tid], c);
        } else {
            wsP[(size_t)blockIdx.x * 64 + tid] = p;
            wsC[(size_t)blockIdx.x * 64 + tid] = c;
        }
    }
}

// ---------------------------------------------------------------------------
// Kernel 2: reduce per-block stats -> aux loss scalar at out[T*K*2]
// ---------------------------------------------------------------------------
__global__ __launch_bounds__(256)
void aux_kernel(const float* __restrict__ wsP,
                const float* __restrict__ wsC,
                float* __restrict__ out, int nblk)
{
    __shared__ float sP[256];
    __shared__ float sC[256];
    const int tid  = threadIdx.x;
    const int e    = tid & 63;
    const int part = tid >> 6;
    float p = 0.f, c = 0.f;
    for (int b = part; b < nblk; b += 4) {
        p += wsP[(size_t)b * 64 + e];
        c += wsC[(size_t)b * 64 + e];
    }
    sP[tid] = p; sC[tid] = c;
    __syncthreads();
    if (tid < 64) {
        p = sP[tid] + sP[tid + 64] + sP[tid + 128] + sP[tid + 192];
        c = sC[tid] + sC[tid + 64] + sC[tid + 128] + sC[tid + 192];
        float val = (c * (1.f / ((float)T_TOKENS * (float)TOPK)))
                  * (p * (1.f / (float)T_TOKENS));
        #pragma unroll
        for (int off = 1; off < 64; off <<= 1) val += __shfl_xor(val, off);
        if (tid == 0) out[(size_t)T_TOKENS * TOPK * 2] = val * (float)NEXP;
    }
}

extern "C" void kernel_launch(void* const* d_in, const int* in_sizes, int n_in,
                              void* d_out, int out_size, void* d_ws, size_t ws_size,
                              hipStream_t stream)
{
    const float* tokens = (const float*)d_in[0];
    const float* W      = (const float*)d_in[1];
    float* out = (float*)d_out;

    const size_t needed = (size_t)NBLK * 64 * 2 * sizeof(float);
    float* ws = (float*)d_ws;

    if (ws_size >= needed) {
        float* wsP = ws;
        float* wsC = ws + (size_t)NBLK * 64;
        router_kernel<<<NBLK, 256, 0, stream>>>(tokens, W, out, wsP, wsC, 0);
        aux_kernel<<<1, 256, 0, stream>>>(wsP, wsC, out, NBLK);
    } else {
        // atomic fallback: 128 floats of scratch
        hipMemsetAsync(d_ws, 0, 128 * sizeof(float), stream);
        float* wsP = ws;
        float* wsC = ws + 64;
        router_kernel<<<NBLK, 256, 0, stream>>>(tokens, W, out, wsP, wsC, 1);
        aux_kernel<<<1, 256, 0, stream>>>(wsP, wsC, out, 1);
    }
}